// Round 13
// baseline (58.627 us; speedup 1.0000x reference)
//
#include <hip/hip_runtime.h>
#include <hip/hip_bf16.h>

#define Nn 8192
#define Mm 1024
#define Dd 1024

typedef __attribute__((ext_vector_type(8))) short short8;
typedef __attribute__((ext_vector_type(4))) short short4v;
typedef __attribute__((ext_vector_type(4))) float f32x4;

typedef const __attribute__((address_space(1))) void* gas_p;
typedef __attribute__((address_space(3))) void* las_p;

// round-to-nearest-even fp32 -> bf16 (bit pattern as short)
__device__ __forceinline__ short f2bf(float f) {
  unsigned u = __builtin_bit_cast(unsigned, f);
  u += 0x7fffu + ((u >> 16) & 1u);
  return (short)(u >> 16);
}

// ---------------- kernel 1: h (fp32) -> A (bf16)  [R1-passed] ----------------
__global__ void conv_h_kernel(const float* __restrict__ h, short* __restrict__ A) {
  long i = (long)blockIdx.x * blockDim.x + threadIdx.x; // 8 elems per thread
  const float4* h4 = (const float4*)h;
  float4 a = h4[2 * i];
  float4 b = h4[2 * i + 1];
  short8 o;
  o[0] = f2bf(a.x); o[1] = f2bf(a.y); o[2] = f2bf(a.z); o[3] = f2bf(a.w);
  o[4] = f2bf(b.x); o[5] = f2bf(b.y); o[6] = f2bf(b.z); o[7] = f2bf(b.w);
  *(short8*)(A + 8 * i) = o;
}

// ---------------- kernel 2: B'[m,d] = bf16(u*w3 + w1); c[m] = u . w2  [R1-passed] ----------------
__global__ void prep_b_kernel(const float* __restrict__ u, const float* __restrict__ w,
                              short* __restrict__ Bp, float* __restrict__ cvec) {
  int m = blockIdx.x;      // 1024 blocks
  int t = threadIdx.x;     // 256 threads, 4 elems each
  float4 uv = ((const float4*)(u + (size_t)m * Dd))[t];
  float4 w1 = ((const float4*)(w))[t];
  float4 w2 = ((const float4*)(w + Dd))[t];
  float4 w3 = ((const float4*)(w + 2 * Dd))[t];
  float p = uv.x * w2.x + uv.y * w2.y + uv.z * w2.z + uv.w * w2.w;
  short4v o;
  o[0] = f2bf(fmaf(uv.x, w3.x, w1.x));
  o[1] = f2bf(fmaf(uv.y, w3.y, w1.y));
  o[2] = f2bf(fmaf(uv.z, w3.z, w1.z));
  o[3] = f2bf(fmaf(uv.w, w3.w, w1.w));
  *(short4v*)(Bp + (size_t)m * Dd + t * 4) = o;

#pragma unroll
  for (int off = 32; off > 0; off >>= 1) p += __shfl_down(p, off);
  __shared__ float sred[4];
  if ((t & 63) == 0) sred[t >> 6] = p;
  __syncthreads();
  if (t == 0) cvec[m] = sred[0] + sred[1] + sred[2] + sred[3];
}

// ---------------- kernel 3: GEMM  S = A @ B'^T + c  (A-direct / B-LDS) ----------------
// 128x128 tile, BK=64, 256 thr = 4 waves (2x2), wave 64x64 (R0-passed math).
// A: bf16 fragments DIRECT global->VGPR (R6-passed addressing: lane -> row
//    lane&15 (+16i), 16B chunk lane>>4; both kk's cover one 128B line/row),
//    X/Y 1-tile-ahead register prefetch (R5-passed skeleton). NO ds_write, NO
//    barrier dependency; L2-resident slice via XCD swizzle (2 MB/XCD).
// B: double-buffered LDS via R0-passed gload_lds staging (pre-swizzled source).
// One s_barrier per tile, preceded by COUNTED s_waitcnt vmcnt(8): per
// half-iteration outstanding = [stageB 4, aNext 8]; vmcnt(8) retires staging
// and leaves the A-prefetch in flight (never drains). Compiler's own aX-use
// wait is vmcnt(12) -- consistent, also never drains the pipeline.
// sched_barrier(0) pins stage-before-loadA issue order (queue arithmetic).
__global__ __launch_bounds__(256) void gemm_adirect_kernel(
    const short* __restrict__ A,   // N x D bf16
    const short* __restrict__ B,   // M x D bf16 (B')
    const float* __restrict__ cvec,// M
    float* __restrict__ out)       // N x M fp32
{
  __shared__ __align__(16) short Bs[2][128 * 64];  // 32 KB

  const int bid = blockIdx.x;
  // bijective XCD swizzle: 512 blocks, 64 per XCD; XCD x: brows [8x,8x+8), all bcols
  const int swz  = (bid & 7) * 64 + (bid >> 3);
  const int brow = swz >> 3;   // 0..63
  const int bcol = swz & 7;    // 0..7

  const int tid  = threadIdx.x;
  const int lane = tid & 63;
  const int wid  = tid >> 6;   // 0..3

  // --- B staging (R0-passed): wave stages 32 rows, 4 gload_lds calls ---
  const int l8 = lane >> 3;
  const int kc = (lane & 7) ^ l8;          // pre-swizzled 16B-chunk index
  const short* Bg = B + (size_t)(bcol * 128 + wid * 32 + l8) * Dd + kc * 8;
  const int BsOff = (wid * 32) * 64;

  // --- fragment geometry (R0-passed): 4 waves as 2x2, wave 64x64 ---
  const int wr = wid >> 1, wc = wid & 1;
  const int brow0 = wc * 64 + (lane & 15);
  const int kb = (lane >> 4) * 16;         // byte offset of 16B chunk in 64B k-slice
  const int sw = (lane & 7) << 4;          // read-side XOR (row&7)<<4

  // --- A direct-global fragment base (R6-passed addressing, bf16) ---
  // lane -> row wr*64 + (lane&15) (+ i*16), k-elems (lane>>4)*8 (+ kk*32 + kt*64)
  const short* Ab = A + (size_t)(brow * 128 + wr * 64 + (lane & 15)) * Dd + (lane >> 4) * 8;

  f32x4 acc[4][4] = {};
  short8 aX[8], aY[8];   // [kk*4+i], literal indices only (rule #20)

#define GLOAD(gp, lp) __builtin_amdgcn_global_load_lds((gas_p)(gp), (las_p)(lp), 16, 0, 0)

#define STAGE_B(buf, kt) do { \
    const short* Bgk_ = Bg + (size_t)(kt) * 64; \
    GLOAD(Bgk_,           &Bs[buf][BsOff]); \
    GLOAD(Bgk_ +  8 * Dd, &Bs[buf][BsOff +  8 * 64]); \
    GLOAD(Bgk_ + 16 * Dd, &Bs[buf][BsOff + 16 * 64]); \
    GLOAD(Bgk_ + 24 * Dd, &Bs[buf][BsOff + 24 * 64]); \
  } while (0)

#define LOAD_A(S, kt) do { \
    const short* ab_ = Ab + (size_t)(kt) * 64; \
    _Pragma("unroll") \
    for (int kk_ = 0; kk_ < 2; ++kk_) \
      _Pragma("unroll") \
      for (int i_ = 0; i_ < 4; ++i_) \
        S[kk_ * 4 + i_] = *(const short8*)(ab_ + kk_ * 32 + (size_t)i_ * 16 * Dd); \
  } while (0)

#define COMPUTE(S, buf) do { \
    _Pragma("unroll") \
    for (int kk_ = 0; kk_ < 2; ++kk_) { \
      short8 bf_[4]; \
      const int ko_ = kk_ * 64 + kb; \
      _Pragma("unroll") \
      for (int j_ = 0; j_ < 4; ++j_) \
        bf_[j_] = *(const short8*)((const char*)&Bs[buf][0] + ((brow0 + j_ * 16) * 128 + (ko_ ^ sw))); \
      _Pragma("unroll") \
      for (int i_ = 0; i_ < 4; ++i_) \
        _Pragma("unroll") \
        for (int j_ = 0; j_ < 4; ++j_) \
          acc[i_][j_] = __builtin_amdgcn_mfma_f32_16x16x32_bf16(S[kk_ * 4 + i_], bf_[j_], acc[i_][j_], 0, 0, 0); \
    } \
  } while (0)

#define VM8  asm volatile("s_waitcnt vmcnt(8)" ::: "memory")
#define BAR  __builtin_amdgcn_s_barrier()
#define SB0  __builtin_amdgcn_sched_barrier(0)

  const int NT = Dd / 64;  // 16 K-tiles (even)

  // prologue: stage B(0) -> buf0, then A(0) -> aX (order pinned)
  STAGE_B(0, 0);
  SB0;
  LOAD_A(aX, 0);
  VM8;   // B(0) resident; aX in flight (compiler waits it before first MFMA)
  BAR;

#pragma unroll 1
  for (int kt = 0; kt < NT - 2; kt += 2) {
    // even tile kt: compute aX/buf0; prefetch B(kt+1)->buf1, A(kt+1)->aY
    STAGE_B(1, kt + 1);
    SB0;
    LOAD_A(aY, kt + 1);
    COMPUTE(aX, 0);
    VM8;   // B(kt+1) resident; aY in flight
    BAR;
    // odd tile kt+1: compute aY/buf1; prefetch B(kt+2)->buf0, A(kt+2)->aX
    STAGE_B(0, kt + 2);
    SB0;
    LOAD_A(aX, kt + 2);
    COMPUTE(aY, 1);
    VM8;   // B(kt+2) resident; aX in flight
    BAR;
  }
  // kt = NT-2 (even): prefetch last tile only
  STAGE_B(1, NT - 1);
  SB0;
  LOAD_A(aY, NT - 1);
  COMPUTE(aX, 0);
  VM8;
  BAR;
  // kt = NT-1 (odd): final tile, no prefetch
  COMPUTE(aY, 1);

#undef GLOAD
#undef STAGE_B
#undef LOAD_A
#undef COMPUTE
#undef VM8
#undef BAR
#undef SB0

  // --- epilogue: S[n,m] = acc + c[m] (R0-passed mapping) ---
  const int n0 = brow * 128 + wr * 64 + (lane >> 4) * 4;
  const int m0 = bcol * 128 + wc * 64 + (lane & 15);
#pragma unroll
  for (int j = 0; j < 4; ++j) {
    const float cm = cvec[m0 + j * 16];
#pragma unroll
    for (int i = 0; i < 4; ++i) {
      float* op = out + (size_t)(n0 + i * 16) * Mm + m0 + j * 16;
#pragma unroll
      for (int r = 0; r < 4; ++r)
        op[(size_t)r * Mm] = acc[i][j][r] + cm;
    }
  }
}

extern "C" void kernel_launch(void* const* d_in, const int* in_sizes, int n_in,
                              void* d_out, int out_size, void* d_ws, size_t ws_size,
                              hipStream_t stream) {
  const float* h = (const float*)d_in[0];
  const float* u = (const float*)d_in[1];
  const float* w = (const float*)d_in[2];
  float* out = (float*)d_out;

  // workspace layout: A bf16 (16MB) | B' bf16 (2MB) | c fp32 (4KB)
  short* Abf = (short*)d_ws;
  short* Bp  = Abf + (size_t)Nn * Dd;
  float* cvec = (float*)(Bp + (size_t)Mm * Dd);

  conv_h_kernel<<<(Nn * Dd / 8) / 256, 256, 0, stream>>>(h, Abf);
  prep_b_kernel<<<Mm, 256, 0, stream>>>(u, w, Bp, cvec);
  gemm_adirect_kernel<<<(Nn / 128) * (Mm / 128), 256, 0, stream>>>(Abf, Bp, cvec, out);
}

// Round 14
// 39.812 us; speedup vs baseline: 1.4726x; 1.4726x over previous
//
#include <hip/hip_runtime.h>
#include <hip/hip_bf16.h>

#define Nn 8192
#define Mm 1024
#define Dd 1024

typedef __attribute__((ext_vector_type(8))) short short8;
typedef __attribute__((ext_vector_type(4))) short short4v;
typedef __attribute__((ext_vector_type(4))) float f32x4;

typedef const __attribute__((address_space(1))) void* gas_p;
typedef __attribute__((address_space(3))) void* las_p;

// round-to-nearest-even fp32 -> bf16 (bit pattern as short)
__device__ __forceinline__ short f2bf(float f) {
  unsigned u = __builtin_bit_cast(unsigned, f);
  u += 0x7fffu + ((u >> 16) & 1u);
  return (short)(u >> 16);
}

// ---------------- kernel 1: h (fp32) -> A (bf16)  [R1-passed] ----------------
__global__ void conv_h_kernel(const float* __restrict__ h, short* __restrict__ A) {
  long i = (long)blockIdx.x * blockDim.x + threadIdx.x; // 8 elems per thread
  const float4* h4 = (const float4*)h;
  float4 a = h4[2 * i];
  float4 b = h4[2 * i + 1];
  short8 o;
  o[0] = f2bf(a.x); o[1] = f2bf(a.y); o[2] = f2bf(a.z); o[3] = f2bf(a.w);
  o[4] = f2bf(b.x); o[5] = f2bf(b.y); o[6] = f2bf(b.z); o[7] = f2bf(b.w);
  *(short8*)(A + 8 * i) = o;
}

// ---------------- kernel 2: B'[m,d] = bf16(u*w3 + w1); c[m] = u . w2  [R1-passed] ----------------
__global__ void prep_b_kernel(const float* __restrict__ u, const float* __restrict__ w,
                              short* __restrict__ Bp, float* __restrict__ cvec) {
  int m = blockIdx.x;      // 1024 blocks
  int t = threadIdx.x;     // 256 threads, 4 elems each
  float4 uv = ((const float4*)(u + (size_t)m * Dd))[t];
  float4 w1 = ((const float4*)(w))[t];
  float4 w2 = ((const float4*)(w + Dd))[t];
  float4 w3 = ((const float4*)(w + 2 * Dd))[t];
  float p = uv.x * w2.x + uv.y * w2.y + uv.z * w2.z + uv.w * w2.w;
  short4v o;
  o[0] = f2bf(fmaf(uv.x, w3.x, w1.x));
  o[1] = f2bf(fmaf(uv.y, w3.y, w1.y));
  o[2] = f2bf(fmaf(uv.z, w3.z, w1.z));
  o[3] = f2bf(fmaf(uv.w, w3.w, w1.w));
  *(short4v*)(Bp + (size_t)m * Dd + t * 4) = o;

#pragma unroll
  for (int off = 32; off > 0; off >>= 1) p += __shfl_down(p, off);
  __shared__ float sred[4];
  if ((t & 63) == 0) sred[t >> 6] = p;
  __syncthreads();
  if (t == 0) cvec[m] = sred[0] + sred[1] + sred[2] + sred[3];
}

// ---------------- kernel 3: GEMM  S = A @ B'^T + c  (high-residency 64x128) ----------------
// Tile 64x128 (BM x BN), BK=64, 256 thr = 4 waves (2x2), wave 32x64 out.
// SINGLE-buffered LDS (As 8KB + Bs 16KB = 24 KB) -> 6 blocks/CU = 24 waves/CU:
// 3x the residency of every prior variant. Loop skeleton is ROUND-0's passed
// structure (stage -> __syncthreads -> compute -> __syncthreads, no prefetch --
// the session's fastest GEMM); per-tile serial chain is masked by the 6-block
// convoy, not by intra-block pipelining (which K=16 tiles can't amortize).
// Staging/fragment/epilogue math byte-identical to R2's PASSED 64x128 kernel.
// XOR swizzle both-sides (pre-swizzled gload source kc=(lane&7)^l8; read addr
// koff^sw). Bijective XCD swizzle (1024 blocks: 128/XCD; same-brow 8 blocks
// consecutive on one XCD -> A-panel L2-hot, B' 2MB L2-resident).
__global__ __launch_bounds__(256) void gemm_kernel(
    const short* __restrict__ A,   // N x D bf16
    const short* __restrict__ B,   // M x D bf16 (B')
    const float* __restrict__ cvec,// M
    float* __restrict__ out)       // N x M fp32
{
  __shared__ __align__(16) short As[64 * 64];    //  8 KB
  __shared__ __align__(16) short Bs[128 * 64];   // 16 KB

  const int bid = blockIdx.x;
  // bijective XCD swizzle: 1024 blocks, 128 per XCD; M-dim fastest within XCD
  const int swz  = (bid & 7) * 128 + (bid >> 3);
  const int brow = swz >> 3;   // 0..127 (64-row panel)
  const int bcol = swz & 7;    // 0..7   (128-col panel)

  const int tid  = threadIdx.x;
  const int lane = tid & 63;
  const int wid  = tid >> 6;   // 0..3

  // --- staging (R2-passed): wave stages A rows [wid*16,+16) (2 calls),
  //     B rows [wid*32,+32) (4 calls); 8 rows x 128B per call, pre-swizzled src ---
  const int l8 = lane >> 3;
  const int kc = (lane & 7) ^ l8;          // pre-swizzled 16B-chunk index
  const short* Ag = A + (size_t)(brow * 64 + wid * 16 + l8) * Dd + kc * 8;
  const short* Bg = B + (size_t)(bcol * 128 + wid * 32 + l8) * Dd + kc * 8;
  const int AsOff = (wid * 16) * 64;
  const int BsOff = (wid * 32) * 64;

  // --- fragment reads (R2-passed): 4 waves as 2x2, wave 32x64 ---
  const int wr = wid >> 1, wc = wid & 1;
  const int arow0 = wr * 32 + (lane & 15);
  const int brow0 = wc * 64 + (lane & 15);
  const int kb = (lane >> 4) * 16;         // 16B chunk within 64B k-slice
  const int sw = (lane & 7) << 4;          // read-side XOR (row&7)<<4

  f32x4 acc[2][4] = {};
  const int NT = Dd / 64;  // 16 K-tiles

#pragma unroll 1
  for (int kt = 0; kt < NT; ++kt) {
    // ---- stage tile kt (single buffer; R0-passed skeleton) ----
    const short* Agk = Ag + (size_t)kt * 64;
    const short* Bgk = Bg + (size_t)kt * 64;
#pragma unroll
    for (int j = 0; j < 2; ++j)
      __builtin_amdgcn_global_load_lds((gas_p)(Agk + j * 8 * Dd),
                                       (las_p)(&As[AsOff + j * 8 * 64]), 16, 0, 0);
#pragma unroll
    for (int j = 0; j < 4; ++j)
      __builtin_amdgcn_global_load_lds((gas_p)(Bgk + j * 8 * Dd),
                                       (las_p)(&Bs[BsOff + j * 8 * 64]), 16, 0, 0);
    __syncthreads();   // drains vmcnt -> tile resident

    // ---- compute (R2-passed math) ----
#pragma unroll
    for (int kk = 0; kk < 2; ++kk) {
      short8 af[2], bfr[4];
      const int koff = kk * 64 + kb;
#pragma unroll
      for (int i = 0; i < 2; ++i)
        af[i] = *(const short8*)((const char*)As + ((arow0 + i * 16) * 128 + (koff ^ sw)));
#pragma unroll
      for (int j = 0; j < 4; ++j)
        bfr[j] = *(const short8*)((const char*)Bs + ((brow0 + j * 16) * 128 + (koff ^ sw)));
#pragma unroll
      for (int i = 0; i < 2; ++i)
#pragma unroll
        for (int j = 0; j < 4; ++j)
          acc[i][j] = __builtin_amdgcn_mfma_f32_16x16x32_bf16(af[i], bfr[j], acc[i][j], 0, 0, 0);
    }
    __syncthreads();   // all reads retired before next stage overwrites
  }

  // --- epilogue: S[n,m] = acc + c[m] (R2-passed mapping) ---
  const int n0 = brow * 64 + wr * 32 + (lane >> 4) * 4;
  const int m0 = bcol * 128 + wc * 64 + (lane & 15);
#pragma unroll
  for (int j = 0; j < 4; ++j) {
    const float cm = cvec[m0 + j * 16];
#pragma unroll
    for (int i = 0; i < 2; ++i) {
      float* op = out + (size_t)(n0 + i * 16) * Mm + m0 + j * 16;
#pragma unroll
      for (int r = 0; r < 4; ++r)
        op[(size_t)r * Mm] = acc[i][j][r] + cm;
    }
  }
}

extern "C" void kernel_launch(void* const* d_in, const int* in_sizes, int n_in,
                              void* d_out, int out_size, void* d_ws, size_t ws_size,
                              hipStream_t stream) {
  const float* h = (const float*)d_in[0];
  const float* u = (const float*)d_in[1];
  const float* w = (const float*)d_in[2];
  float* out = (float*)d_out;

  // workspace layout: A bf16 (16MB) | B' bf16 (2MB) | c fp32 (4KB)
  short* Abf = (short*)d_ws;
  short* Bp  = Abf + (size_t)Nn * Dd;
  float* cvec = (float*)(Bp + (size_t)Mm * Dd);

  conv_h_kernel<<<(Nn * Dd / 8) / 256, 256, 0, stream>>>(h, Abf);
  prep_b_kernel<<<Mm, 256, 0, stream>>>(u, w, Bp, cvec);
  gemm_kernel<<<(Nn / 64) * (Mm / 128), 256, 0, stream>>>(Abf, Bp, cvec, out);
}